// Round 1
// baseline (51.008 us; speedup 1.0000x reference)
//
#include <hip/hip_runtime.h>
#include <hip/hip_bf16.h>

typedef __bf16 bf16x8 __attribute__((ext_vector_type(8)));
typedef float  f32x4  __attribute__((ext_vector_type(4)));

#define MAIN_BLOCKS 2048

// Each wave processes tiles of 16 states with mfma_f32_16x16x32_bf16.
// A-frag: lane holds A[m=lane&15][k=8*(lane>>4)+e (+32 for kstep1)]  (h1, computed in-place)
// B-frag: lane holds B[k=8*(lane>>4)+e+32*ks][n=(lane&15)+16*t]     (W2, preloaded)
// D:      lane holds C[m=4*(lane>>4)+r][n=(lane&15)+16*t]           (verified layout)
// Only sum over all (state, hidden) cells is needed -> no cross-lane epilogue.
__global__ __launch_bounds__(256) void qloss_main(
    const float* __restrict__ states, const float* __restrict__ W1,
    const float* __restrict__ b1, const float* __restrict__ W2,
    const float* __restrict__ b2, const float* __restrict__ W3,
    int n_states, double* __restrict__ partials)
{
    const int lane = threadIdx.x & 63;
    const int wave = threadIdx.x >> 6;
    const int g = lane >> 4;     // k-group 0..3
    const int r = lane & 15;     // row within A-tile / col within D-tile

    // ---- per-lane constant preload ----
    float w1r[4][16], b1r[16];
#pragma unroll
    for (int j = 0; j < 16; ++j) {
        const int k = 8*g + (j & 7) + 32*(j >> 3);
        b1r[j] = b1[k];
#pragma unroll
        for (int i = 0; i < 4; ++i) w1r[i][j] = W1[i*64 + k];
    }

    bf16x8 w2f[4][2];
#pragma unroll
    for (int t = 0; t < 4; ++t)
#pragma unroll
        for (int ks = 0; ks < 2; ++ks)
#pragma unroll
            for (int e = 0; e < 8; ++e) {
                const int k = 8*g + e + 32*ks;
                w2f[t][ks][e] = (__bf16)W2[k*64 + (r + 16*t)];
            }

    float b2r[4], w3r[4];
#pragma unroll
    for (int t = 0; t < 4; ++t) { b2r[t] = b2[r + 16*t]; w3r[t] = W3[r + 16*t]; }

    const int ntiles = n_states >> 4;
    const int waves_per_blk = blockDim.x >> 6;
    const int nwaves = gridDim.x * waves_per_blk;
    const float4* __restrict__ st4 = (const float4*)states;

    float psum = 0.f;
    for (int tile = blockIdx.x * waves_per_blk + wave; tile < ntiles; tile += nwaves) {
        const float4 x = st4[tile*16 + r];   // lanes 16..63 replicate lanes 0..15 (HW merges)

        // layer 1: h1 = relu(x@W1 + b1), produced directly in A-fragment layout
        bf16x8 af[2];
#pragma unroll
        for (int ks = 0; ks < 2; ++ks)
#pragma unroll
            for (int e = 0; e < 8; ++e) {
                const int j = ks*8 + e;
                float t = fmaf(x.x, w1r[0][j], b1r[j]);
                t = fmaf(x.y, w1r[1][j], t);
                t = fmaf(x.z, w1r[2][j], t);
                t = fmaf(x.w, w1r[3][j], t);
                af[ks][e] = (__bf16)fmaxf(t, 0.f);
            }

        // layer 2 (MFMA, b2 folded into acc init) + epilogue (relu * W3)
#pragma unroll
        for (int t4 = 0; t4 < 4; ++t4) {
            f32x4 acc = { b2r[t4], b2r[t4], b2r[t4], b2r[t4] };
            acc = __builtin_amdgcn_mfma_f32_16x16x32_bf16(af[0], w2f[t4][0], acc, 0, 0, 0);
            acc = __builtin_amdgcn_mfma_f32_16x16x32_bf16(af[1], w2f[t4][1], acc, 0, 0, 0);
#pragma unroll
            for (int rr = 0; rr < 4; ++rr)
                psum = fmaf(fmaxf(acc[rr], 0.f), w3r[t4], psum);
        }
    }

    // ---- block reduction -> one double partial per block ----
#pragma unroll
    for (int off = 32; off; off >>= 1) psum += __shfl_xor(psum, off, 64);
    __shared__ float wpart[4];
    if (lane == 0) wpart[wave] = psum;
    __syncthreads();
    if (threadIdx.x == 0)
        partials[blockIdx.x] = (double)(wpart[0] + wpart[1] + wpart[2] + wpart[3]);
}

// 1 block, 256 threads: wave w computes net(e_w) in fp32; thread 0 combines.
__global__ __launch_bounds__(256) void qloss_finalize(
    const float* __restrict__ W1, const float* __restrict__ b1,
    const float* __restrict__ W2, const float* __restrict__ b2,
    const float* __restrict__ W3, const float* __restrict__ b3,
    const double* __restrict__ partials, int nparts,
    int n_states, float* __restrict__ out)
{
    const int lane = threadIdx.x & 63;
    const int wave = threadIdx.x >> 6;

    __shared__ float  dlog[4];
    __shared__ double wsum[4];

    // denominator logits: one-hot state index == wave
    float h1 = fmaxf(W1[wave*64 + lane] + b1[lane], 0.f);
    float acc = b2[lane];
    for (int k = 0; k < 64; ++k)
        acc = fmaf(__shfl(h1, k, 64), W2[k*64 + lane], acc);
    float c = fmaxf(acc, 0.f) * W3[lane];
#pragma unroll
    for (int off = 32; off; off >>= 1) c += __shfl_xor(c, off, 64);
    if (lane == 0) dlog[wave] = c + b3[0];

    // sum block partials
    double ps = 0.0;
    for (int i = threadIdx.x; i < nparts; i += blockDim.x) ps += partials[i];
#pragma unroll
    for (int off = 32; off; off >>= 1) ps += __shfl_xor(ps, off, 64);
    if (lane == 0) wsum[wave] = ps;

    __syncthreads();
    if (threadIdx.x == 0) {
        const double S = wsum[0] + wsum[1] + wsum[2] + wsum[3];
        double m = dlog[0];
        for (int i = 1; i < 4; ++i) m = fmax(m, (double)dlog[i]);
        double e = 0.0;
        for (int i = 0; i < 4; ++i) e += exp((double)dlog[i] - m);
        const double lse = m + log(e);
        const double nn = (double)n_states;
        const double logits_sum = S + nn * (double)b3[0];
        out[0] = (float)(-(logits_sum - nn * lse));
    }
}

extern "C" void kernel_launch(void* const* d_in, const int* in_sizes, int n_in,
                              void* d_out, int out_size, void* d_ws, size_t ws_size,
                              hipStream_t stream)
{
    const float* states = (const float*)d_in[0];
    const float* W1 = (const float*)d_in[1];
    const float* b1 = (const float*)d_in[2];
    const float* W2 = (const float*)d_in[3];
    const float* b2 = (const float*)d_in[4];
    const float* W3 = (const float*)d_in[5];
    const float* b3 = (const float*)d_in[6];
    float* out = (float*)d_out;

    const int n_states = in_sizes[0] / 4;

    int nb = MAIN_BLOCKS;
    const size_t max_parts = ws_size / sizeof(double);
    if ((size_t)nb > max_parts) nb = (int)max_parts;
    if (nb < 1) nb = 1;
    double* partials = (double*)d_ws;

    qloss_main<<<nb, 256, 0, stream>>>(states, W1, b1, W2, b2, W3, n_states, partials);
    qloss_finalize<<<1, 256, 0, stream>>>(W1, b1, W2, b2, W3, b3, partials, nb, n_states, out);
}